// Round 2
// baseline (181.477 us; speedup 1.0000x reference)
//
#include <hip/hip_runtime.h>
#include <stdint.h>

// Sampler_6107443495068 — vLLM-style sampler on MI355X.
// One block per row (B=128 blocks, 1024 threads). Single streaming pass over
// V=128000 logits: online logsumexp + collect candidates with raw >= 2.5
// (everything that can matter for top-20 logprobs / top-k<=63 sampling).
// Penalties recomputed per-candidate from LDS bitmap+hash. Bitonic sorts in
// LDS. Gumbel noise = exact JAX threefry2x32(key=42).
// R1: RNG fixed to partitionable 32-bit path = (x0 ^ x1) of
//     threefry(key, (hi32(i), lo32(i))) — JAX default since 0.4.36.

#define NTHREADS 1024
#define BITWORDS 4000          // 128000 / 32
#define HASHSZ   1024
#define CANDCAP  2048
#define CUTKEY   0xC0200000u   // fkey(2.5f)
#define HASH_EMPTY 0xFFFFFFFFu
#define NEG_INF_F -3.402823466e38f   // jnp.finfo(f32).min

__device__ __forceinline__ uint32_t fkey(float f) {
  uint32_t u = __float_as_uint(f);
  return (u & 0x80000000u) ? ~u : (u | 0x80000000u);
}
__device__ __forceinline__ float funkey(uint32_t k) {
  uint32_t u = (k & 0x80000000u) ? (k & 0x7FFFFFFFu) : ~k;
  return __uint_as_float(u);
}

__device__ __forceinline__ void threefry(uint32_t x0, uint32_t x1,
                                         uint32_t &o0, uint32_t &o1) {
  const uint32_t ks0 = 0u, ks1 = 42u, ks2 = 0u ^ 42u ^ 0x1BD11BDAu;
  x0 += ks0; x1 += ks1;
#define TF_R(r) { x0 += x1; x1 = (x1 << (r)) | (x1 >> (32 - (r))); x1 ^= x0; }
  TF_R(13) TF_R(15) TF_R(26) TF_R(6)
  x0 += ks1; x1 += ks2 + 1u;
  TF_R(17) TF_R(29) TF_R(16) TF_R(24)
  x0 += ks2; x1 += ks0 + 2u;
  TF_R(13) TF_R(15) TF_R(26) TF_R(6)
  x0 += ks0; x1 += ks1 + 3u;
  TF_R(17) TF_R(29) TF_R(16) TF_R(24)
  x0 += ks1; x1 += ks2 + 4u;
  TF_R(13) TF_R(15) TF_R(26) TF_R(6)
  x0 += ks2; x1 += ks0 + 5u;
#undef TF_R
  o0 = x0; o1 = x1;
}

// jax.random.uniform(key(42), minval=1e-10, maxval=1.0), then -log(-log(u)).
// RNG_VARIANT 0: partitionable (JAX >= 0.4.36 default), 32-bit draw:
//   bits[i] = x0 ^ x1 of threefry(key, (hi32(i), lo32(i))).
// RNG_VARIANT 1: partitionable but taking x1 only (tried R0 — wrong).
// RNG_VARIANT 2: legacy: i<N/2 -> x0 of (i, i+N/2); else x1 of (i-N/2, i).
#define RNG_VARIANT 0
__device__ __forceinline__ float gumbel_at(uint64_t flat, uint64_t N) {
  uint32_t o0, o1, bits;
#if RNG_VARIANT == 0
  threefry((uint32_t)(flat >> 32), (uint32_t)flat, o0, o1);
  bits = o0 ^ o1;
#elif RNG_VARIANT == 1
  threefry((uint32_t)(flat >> 32), (uint32_t)flat, o0, o1);
  bits = o1;
#else
  uint64_t half = N >> 1;
  if (flat < half) { threefry((uint32_t)flat, (uint32_t)(flat + half), o0, o1); bits = o0; }
  else             { threefry((uint32_t)(flat - half), (uint32_t)flat, o0, o1); bits = o1; }
#endif
  float f = __uint_as_float((bits >> 9) | 0x3F800000u) - 1.0f;  // [0,1)
  float u = fmaxf(1e-10f, f + 1e-10f);  // (maxval-minval) rounds to 1.0f
  return -logf(-logf(u));
}

__device__ __forceinline__ void bitonic_desc(uint64_t* a, int npad, int tid) {
  for (int ksz = 2; ksz <= npad; ksz <<= 1) {
    for (int j = ksz >> 1; j > 0; j >>= 1) {
      for (int i = tid; i < npad; i += NTHREADS) {
        int ixj = i ^ j;
        if (ixj > i) {
          uint64_t x = a[i], y = a[ixj];
          bool up = (i & ksz) == 0;
          if (up ? (x < y) : (x > y)) { a[i] = y; a[ixj] = x; }
        }
      }
      __syncthreads();
    }
  }
}

__global__ __launch_bounds__(NTHREADS)
void sampler_kernel(const float* __restrict__ logits,
                    const float* __restrict__ temperature,
                    const float* __restrict__ presence,
                    const float* __restrict__ frequency,
                    const float* __restrict__ repetition,
                    const float* __restrict__ top_p,
                    const int* __restrict__ prompt_ids,
                    const int* __restrict__ output_ids,
                    const int* __restrict__ output_lens,
                    const int* __restrict__ stop_ids,
                    const int* __restrict__ min_tokens,
                    const int* __restrict__ top_k,
                    float* __restrict__ out,
                    int B, int V, int P, int O, int S, int NL)
{
  __shared__ uint32_t sh_bitmap[BITWORDS];
  __shared__ uint32_t sh_hash[HASHSZ];
  __shared__ uint64_t sh_cand[CANDCAP];
  __shared__ uint64_t sh_sort[CANDCAP];
  __shared__ float    sh_eval[CANDCAP];
  __shared__ float    sh_redm[16], sh_reds[16];
  __shared__ int      sh_redi[16];
  __shared__ int      sh_n;
  __shared__ float    sh_M, sh_logS;
  __shared__ int      sh_s, sh_fin;

  const int row = blockIdx.x;
  const int tid = threadIdx.x;

  const float temp = temperature[row];
  const float pres = presence[row];
  const float freq = frequency[row];
  const float rep  = repetition[row];
  const float topp = top_p[row];
  const int   olen = output_lens[row];
  const int   mint = min_tokens[row];
  int k = top_k[row]; if (k < 1) k = 1; if (k > V) k = V;
  const bool  penal = olen < mint;
  const int   s0 = stop_ids[row*S + 0], s1 = stop_ids[row*S + 1];
  const int   s2 = stop_ids[row*S + 2], s3 = stop_ids[row*S + 3];
  const float temp_eff = (temp < 1e-5f) ? 1.0f : temp;

  // ---- Phase 0: init LDS ----
  for (int i = tid; i < BITWORDS; i += NTHREADS) sh_bitmap[i] = 0u;
  for (int i = tid; i < HASHSZ;   i += NTHREADS) sh_hash[i] = HASH_EMPTY;
  if (tid == 0) sh_n = 0;
  __syncthreads();

  // ---- Phase 1: build seen-bitmap + out-count hash ----
  for (int i = tid; i < P; i += NTHREADS) {
    int v = prompt_ids[(size_t)row * P + i];
    atomicOr(&sh_bitmap[v >> 5], 1u << (v & 31));
  }
  for (int i = tid; i < O; i += NTHREADS) {
    if (i < olen) {
      int v = output_ids[(size_t)row * O + i];
      atomicOr(&sh_bitmap[v >> 5], 1u << (v & 31));
      uint32_t h = ((uint32_t)v * 2654435761u) & (HASHSZ - 1);
      for (;;) {
        uint32_t old = atomicCAS(&sh_hash[h], HASH_EMPTY, ((uint32_t)v << 10) | 1u);
        if (old == HASH_EMPTY) break;
        if ((old >> 10) == (uint32_t)v) { atomicAdd(&sh_hash[h], 1u); break; }
        h = (h + 1) & (HASHSZ - 1);
      }
    }
  }
  __syncthreads();

  // ---- Phase 2: stream logits: online logsumexp + collect candidates ----
  const float4* lg4 = (const float4*)(logits + (size_t)row * V);
  const int nv4 = V >> 2;
  float m = -__builtin_inff(), ssum = 0.0f;
  for (int i = tid; i < nv4; i += NTHREADS) {
    float4 f4 = lg4[i];
    float xs[4] = {f4.x, f4.y, f4.z, f4.w};
    int vbase = i << 2;
#pragma unroll
    for (int j = 0; j < 4; j++) {
      float x = xs[j];
      if (x > m) { ssum = ssum * expf(m - x) + 1.0f; m = x; }
      else       { ssum += expf(x - m); }
      uint32_t key = fkey(x);
      if (key >= CUTKEY) {
        int slot = atomicAdd(&sh_n, 1);
        if (slot < CANDCAP)
          sh_cand[slot] = ((uint64_t)key << 32) | (uint32_t)(~(uint32_t)(vbase + j));
      }
    }
  }
  for (int off = 1; off < 64; off <<= 1) {
    float mo = __shfl_xor(m, off);
    float so = __shfl_xor(ssum, off);
    float M = fmaxf(m, mo);
    ssum = ssum * expf(m - M) + so * expf(mo - M);
    m = M;
  }
  if ((tid & 63) == 0) { sh_redm[tid >> 6] = m; sh_reds[tid >> 6] = ssum; }
  __syncthreads();
  if (tid == 0) {
    float M = sh_redm[0], Ss = sh_reds[0];
    for (int w = 1; w < 16; w++) {
      float mo = sh_redm[w], so = sh_reds[w];
      float MM = fmaxf(M, mo);
      Ss = Ss * expf(M - MM) + so * expf(mo - MM);
      M = MM;
    }
    sh_M = M; sh_logS = logf(Ss);
  }
  __syncthreads();

  const int n = (sh_n < CANDCAP) ? sh_n : CANDCAP;
  int npad = 32; while (npad < n) npad <<= 1;
  for (int i = tid; i < npad; i += NTHREADS) if (i >= n) sh_cand[i] = 0ull;
  __syncthreads();

  // ---- Phase 3: sort raw candidates desc (key desc, idx asc) ----
  bitonic_desc(sh_cand, npad, tid);

  // top-NL logprobs/indices (raw logits, RNG-free)
  if (tid < NL && tid < n) {
    uint64_t c = sh_cand[tid];
    float val = funkey((uint32_t)(c >> 32));
    int   idx = (int)(~(uint32_t)c);
    out[B + (size_t)row * NL + tid]          = (val - sh_M) - sh_logS;
    out[B + (size_t)B * NL + (size_t)row * NL + tid] = (float)idx;
  }

  // ---- Phase 4: penalized composites, sort ----
  for (int i = tid; i < npad; i += NTHREADS) {
    if (i < n) {
      uint64_t c = sh_cand[i];
      float l = funkey((uint32_t)(c >> 32));
      int  v  = (int)(~(uint32_t)c);
      if (penal && (v == s0 || v == s1 || v == s2 || v == s3)) l = NEG_INF_F;
      bool seen = (sh_bitmap[v >> 5] >> (v & 31)) & 1u;
      if (seen) {
        l = (l > 0.0f) ? (l / rep) : (l * rep);
        uint32_t h = ((uint32_t)v * 2654435761u) & (HASHSZ - 1);
        uint32_t cnt = 0;
        for (;;) {
          uint32_t x = sh_hash[h];
          if (x == HASH_EMPTY) break;
          if ((x >> 10) == (uint32_t)v) { cnt = x & 1023u; break; }
          h = (h + 1) & (HASHSZ - 1);
        }
        if (cnt) {
          float t = __fmul_rn(freq, (float)cnt);
          l = __fsub_rn(l, t);          // logits - freq*counts
          l = __fsub_rn(l, pres);       // logits - pres*1.0
        }
      }
      sh_sort[i] = ((uint64_t)fkey(l) << 32) | (uint32_t)(~(uint32_t)v);
    } else {
      sh_sort[i] = 0ull;
    }
  }
  __syncthreads();
  bitonic_desc(sh_sort, npad, tid);

  // ---- Phase 5: top-k survivors (value >= k-th largest, ties kept) ----
  if (tid == 0) {
    uint32_t tkey = (uint32_t)(sh_sort[(k <= n ? k : n) - 1] >> 32);
    int lo = (k <= n ? k : n), hi = n;
    while (lo < hi) {
      int mid = (lo + hi) >> 1;
      if ((uint32_t)(sh_sort[mid] >> 32) >= tkey) lo = mid + 1; else hi = mid;
    }
    sh_s = lo;
  }
  __syncthreads();
  const int s = sh_s;

  // ---- Phase 6: softmax over survivors (desc order), top-p prefix cut ----
  const float g0 = funkey((uint32_t)(sh_sort[0] >> 32)) / temp_eff;
  for (int i = tid; i < s; i += NTHREADS) {
    float gi = funkey((uint32_t)(sh_sort[i] >> 32)) / temp_eff;
    sh_eval[i] = expf(gi - g0);
  }
  __syncthreads();
  if (tid == 0) {
    float Z = 0.0f;
    for (int i = s - 1; i >= 0; i--) Z += sh_eval[i];   // ascending-order sum
    const float thresh = 1.0f - topp;
    float cum = 0.0f; int jcut = 0;
    for (int j = 0; j < s; j++) {          // ascending value order
      cum += sh_eval[s - 1 - j] / Z;
      if (cum <= thresh) jcut = j + 1; else break;
    }
    if (jcut > s - 1) jcut = s - 1;        // largest is never masked
    sh_fin = s - jcut;                     // survivors = desc positions [0, sfin)
  }
  __syncthreads();
  const int sfin = sh_fin;

  // ---- Phase 7: gumbel argmax over final survivors ----
  float best = -__builtin_inff(); int bestIdx = 0x7FFFFFFF;
  for (int i = tid; i < sfin; i += NTHREADS) {
    uint64_t c = sh_sort[i];
    int v = (int)(~(uint32_t)c);
    float gi = funkey((uint32_t)(c >> 32)) / temp_eff;
    float tot = gi + gumbel_at((uint64_t)row * (uint64_t)V + (uint64_t)v,
                               (uint64_t)B * (uint64_t)V);
    if (tot > best || (tot == best && v < bestIdx)) { best = tot; bestIdx = v; }
  }
  for (int off = 1; off < 64; off <<= 1) {
    float bo = __shfl_xor(best, off);
    int   io = __shfl_xor(bestIdx, off);
    if (bo > best || (bo == best && io < bestIdx)) { best = bo; bestIdx = io; }
  }
  if ((tid & 63) == 0) { sh_redm[tid >> 6] = best; sh_redi[tid >> 6] = bestIdx; }
  __syncthreads();
  if (tid == 0) {
    float bb = sh_redm[0]; int bi = sh_redi[0];
    for (int w = 1; w < 16; w++) {
      float bo = sh_redm[w]; int io = sh_redi[w];
      if (bo > bb || (bo == bb && io < bi)) { bb = bo; bi = io; }
    }
    int greedy = (int)(~(uint32_t)sh_sort[0]);        // argmax, lowest idx on tie
    int sampled = (temp < 1e-5f) ? greedy : bi;
    out[row] = (float)sampled;
  }
}

extern "C" void kernel_launch(void* const* d_in, const int* in_sizes, int n_in,
                              void* d_out, int out_size, void* d_ws, size_t ws_size,
                              hipStream_t stream) {
  const float* logits      = (const float*)d_in[0];
  const float* temperature = (const float*)d_in[1];
  const float* presence    = (const float*)d_in[2];
  const float* frequency   = (const float*)d_in[3];
  const float* repetition  = (const float*)d_in[4];
  const float* top_p       = (const float*)d_in[5];
  const int*   prompt_ids  = (const int*)d_in[6];
  const int*   output_ids  = (const int*)d_in[7];
  const int*   output_lens = (const int*)d_in[8];
  const int*   stop_ids    = (const int*)d_in[9];
  const int*   min_tokens  = (const int*)d_in[10];
  const int*   top_k       = (const int*)d_in[11];
  float* out = (float*)d_out;

  const int B  = in_sizes[1];
  const int V  = in_sizes[0] / B;
  const int P  = in_sizes[6] / B;
  const int O  = in_sizes[7] / B;
  const int S  = in_sizes[9] / B;
  const int NL = (out_size / B - 1) / 2;

  sampler_kernel<<<B, NTHREADS, 0, stream>>>(
      logits, temperature, presence, frequency, repetition, top_p,
      prompt_ids, output_ids, output_lens, stop_ids, min_tokens, top_k,
      out, B, V, P, O, S, NL);
}